// Round 6
// baseline (234.249 us; speedup 1.0000x reference)
//
#include <hip/hip_runtime.h>

// LIF neuron scan over STEP=4 timesteps.
// x: [4, 64, 128, 32, 32] fp32; out same shape.
// Per element: mem = mem*0.25 + x_t; spike = mem > 0.5; mem *= (1-spike).
//
// History: R1 (serialized loads), R4 (sched_barrier), R5 (asm vmcnt
// pipeline) all ~81 us, identical counters -> wave-level MLP was never
// the bottleneck (20 KB/CU in flight >> 10 KB needed at 400 ns).
// Counter evidence: FETCH_SIZE = 65.5 MB = exactly HALF the input.
// x is L3-resident at kernel start (harness restore); our own output
// stores write-allocate in L2/L3 and evict x mid-kernel, forcing half
// the reads to HBM and mixing read+eviction streams.
// R6: nontemporal stores on the coalesced layout (R3's nt regression
// was its stride-32B lane layout -> partial-line sectors -> 150 MB
// writes; here each store instr covers a full contiguous 1 KB).
// Output is write-once -> bypass caches, keep x resident in L3.

#define DECAY 0.25f

typedef float v4f __attribute__((ext_vector_type(4)));

__device__ __forceinline__ v4f lif_step(v4f& mem, const v4f xv) {
    mem = mem * DECAY + xv;                    // leaky integrate
    v4f s;
    s.x = mem.x > 0.5f ? 1.f : 0.f;
    s.y = mem.y > 0.5f ? 1.f : 0.f;
    s.z = mem.z > 0.5f ? 1.f : 0.f;
    s.w = mem.w > 0.5f ? 1.f : 0.f;
    mem.x = (s.x != 0.f) ? 0.f : mem.x;        // reset where spiked
    mem.y = (s.y != 0.f) ? 0.f : mem.y;
    mem.z = (s.z != 0.f) ? 0.f : mem.z;
    mem.w = (s.w != 0.f) ? 0.f : mem.w;
    return s;
}

__global__ __launch_bounds__(256) void lif_kernel(const v4f* __restrict__ x,
                                                  v4f* __restrict__ out,
                                                  int n4) {
    // One float4 granule per thread, stride-1 across the wave: every
    // load/store instruction covers a full contiguous 1 KB (64B-line
    // aligned) -> nontemporal stores stream whole lines, no sectoring.
    int i = blockIdx.x * blockDim.x + threadIdx.x;
    if (i >= n4) return;

    v4f mem = (v4f)(0.f);

#pragma unroll
    for (int t = 0; t < 4; ++t) {
        v4f xv = x[(size_t)t * n4 + i];
        v4f s = lif_step(mem, xv);
        __builtin_nontemporal_store(s, &out[(size_t)t * n4 + i]);
    }
}

extern "C" void kernel_launch(void* const* d_in, const int* in_sizes, int n_in,
                              void* d_out, int out_size, void* d_ws, size_t ws_size,
                              hipStream_t stream) {
    const float* x = (const float*)d_in[0];
    float* out = (float*)d_out;

    int n = in_sizes[0];       // 4 * 64 * 128 * 32 * 32 = 33,554,432
    int n4 = n / 16;           // per-timestep float4 granule count = 2,097,152

    int block = 256;
    int grid = (n4 + block - 1) / block;   // 8192 blocks

    lif_kernel<<<grid, block, 0, stream>>>((const v4f*)x, (v4f*)out, n4);
}